// Round 13
// baseline (210.375 us; speedup 1.0000x reference)
//
#include <hip/hip_runtime.h>
#include <hip/hip_bf16.h>

// B=4, S=4096, D=512, FH=2048, H=64
// outputs: progress (B*S) ++ forecast (B*S) ++ fore (B*S*D), all f32
//
// Structure:
//   trans: W1t = bf16(W1^T) via LDS tiles + gxbias
//   prep:  Weffb = bf16(W2@W1) [MFMA, f32-A], beff, Gx [MFMA, f32 A/B]
//   K1: fixed-point A0 + ALL 1024 fore tiles (A = x f32, XCD-swizzled)
//   K2: fixed-point B0 + 128 Gf tiles (A = fore f32 from d_out)
//   K3: fixed-point A1 (scan only);  K4: B1 (scan only, stores c_hist/p)
//   finish: forecast cells + broadcasts

#if __has_builtin(__builtin_amdgcn_exp2f)
__device__ __forceinline__ float EXP2(float x) { return __builtin_amdgcn_exp2f(x); }
#else
__device__ __forceinline__ float EXP2(float x) { return __expf(x * 0.6931471805599453f); }
#endif
#if __has_builtin(__builtin_amdgcn_rcpf)
__device__ __forceinline__ float RCPF(float x) { return __builtin_amdgcn_rcpf(x); }
#else
__device__ __forceinline__ float RCPF(float x) { return 1.0f / x; }
#endif

constexpr float L2E  = 1.4426950408889634f;
constexpr float L2E2 = 2.8853900817779268f;

__device__ __forceinline__ float fsig(float x) { return 1.0f / (1.0f + __expf(-x)); }
__device__ __forceinline__ float ftanh(float x) { return 1.0f - 2.0f / (1.0f + __expf(2.0f * x)); }
__device__ __forceinline__ float sig_f(float x)  { return RCPF(1.0f + EXP2(-L2E * x)); }
__device__ __forceinline__ float tanh_f(float x) { return fmaf(-2.0f, RCPF(1.0f + EXP2(L2E2 * x)), 1.0f); }

template<int CTRL>
__device__ __forceinline__ float dppadd(float x) {
    return x + __int_as_float(__builtin_amdgcn_update_dpp(
        0, __float_as_int(x), CTRL, 0xf, 0xf, true));
}
__device__ __forceinline__ float dpp_sum64_lane63(float x) {
    x = dppadd<0x111>(x); x = dppadd<0x112>(x); x = dppadd<0x114>(x);
    x = dppadd<0x118>(x); x = dppadd<0x142>(x); x = dppadd<0x143>(x);
    return x;
}
__device__ __forceinline__ float readlane63(float x) {
    return __int_as_float(__builtin_amdgcn_readlane(__float_as_int(x), 63));
}
__device__ __forceinline__ float readlane_s(float x, int s) {
    return __int_as_float(__builtin_amdgcn_readlane(__float_as_int(x), s));
}

using bf16x8 = __attribute__((ext_vector_type(8))) __bf16;
using f32x4  = __attribute__((ext_vector_type(4))) float;

// fragment loaders: bf16 direct, f32 with in-register RNE conversion
__device__ __forceinline__ bf16x8 ld_frag(const __hip_bfloat16* __restrict__ p) {
    return *reinterpret_cast<const bf16x8*>(p);
}
__device__ __forceinline__ bf16x8 ld_frag(const float* __restrict__ p) {
    const float4 v0 = *reinterpret_cast<const float4*>(p);
    const float4 v1 = *reinterpret_cast<const float4*>(p + 4);
    bf16x8 r;
    r[0] = __builtin_bit_cast(__bf16, __float2bfloat16(v0.x));
    r[1] = __builtin_bit_cast(__bf16, __float2bfloat16(v0.y));
    r[2] = __builtin_bit_cast(__bf16, __float2bfloat16(v0.z));
    r[3] = __builtin_bit_cast(__bf16, __float2bfloat16(v0.w));
    r[4] = __builtin_bit_cast(__bf16, __float2bfloat16(v1.x));
    r[5] = __builtin_bit_cast(__bf16, __float2bfloat16(v1.y));
    r[6] = __builtin_bit_cast(__bf16, __float2bfloat16(v1.z));
    r[7] = __builtin_bit_cast(__bf16, __float2bfloat16(v1.w));
    return r;
}

// ---------------------------------------------------------------------------
// MFMA 128x64 tile (4 waves; wave w covers rows {bm+w*16, bm+64+w*16}).
// A: [M][lda] row-major (k contiguous), f32 or bf16. B: [N][ldb] (B^T layout).
// mfma_f32_16x16x32_bf16 layouts (verified round 11):
//   A/B-frag lane l: row/col = l&15, k = (l>>4)*8 + j
//   D        lane l: col = l&15, row = (l>>4)*4 + i
// ---------------------------------------------------------------------------
template<typename TA, typename TB>
__device__ __forceinline__ void mfma_tile128(
    const TA* __restrict__ A, int lda,
    const TB* __restrict__ B, int ldb,
    int K, int bm, int bn,
    const float* __restrict__ bias,                 // nullptr -> none
    float* __restrict__ Cf, int ldc,                // nullptr -> skip
    __hip_bfloat16* __restrict__ Cb)                // nullptr -> skip (same ldc)
{
    const int w    = threadIdx.x >> 6;
    const int lane = threadIdx.x & 63;
    const int rc   = lane & 15;
    const int kg   = lane >> 4;
    const TA* ap0 = A + (size_t)(bm + w * 16 + rc) * lda + kg * 8;
    const TA* ap1 = ap0 + (size_t)64 * lda;
    const TB* bp0 = B + (size_t)(bn + rc) * ldb + kg * 8;
    const TB* bp1 = bp0 + (size_t)16 * ldb;
    const TB* bp2 = bp0 + (size_t)32 * ldb;
    const TB* bp3 = bp0 + (size_t)48 * ldb;

    const f32x4 z{0.f, 0.f, 0.f, 0.f};
    f32x4 c00 = z, c01 = z, c02 = z, c03 = z;
    f32x4 c10 = z, c11 = z, c12 = z, c13 = z;

    bf16x8 a0 = ld_frag(ap0), a1 = ld_frag(ap1);
    bf16x8 b0 = ld_frag(bp0), b1 = ld_frag(bp1);
    bf16x8 b2 = ld_frag(bp2), b3 = ld_frag(bp3);
    const int nst = K >> 5;
    for (int s = 1; s <= nst; ++s) {
        bf16x8 a0n = a0, a1n = a1, b0n = b0, b1n = b1, b2n = b2, b3n = b3;
        if (s < nst) {
            const int k0 = s << 5;
            a0n = ld_frag(ap0 + k0); a1n = ld_frag(ap1 + k0);
            b0n = ld_frag(bp0 + k0); b1n = ld_frag(bp1 + k0);
            b2n = ld_frag(bp2 + k0); b3n = ld_frag(bp3 + k0);
        }
        c00 = __builtin_amdgcn_mfma_f32_16x16x32_bf16(a0, b0, c00, 0, 0, 0);
        c01 = __builtin_amdgcn_mfma_f32_16x16x32_bf16(a0, b1, c01, 0, 0, 0);
        c02 = __builtin_amdgcn_mfma_f32_16x16x32_bf16(a0, b2, c02, 0, 0, 0);
        c03 = __builtin_amdgcn_mfma_f32_16x16x32_bf16(a0, b3, c03, 0, 0, 0);
        c10 = __builtin_amdgcn_mfma_f32_16x16x32_bf16(a1, b0, c10, 0, 0, 0);
        c11 = __builtin_amdgcn_mfma_f32_16x16x32_bf16(a1, b1, c11, 0, 0, 0);
        c12 = __builtin_amdgcn_mfma_f32_16x16x32_bf16(a1, b2, c12, 0, 0, 0);
        c13 = __builtin_amdgcn_mfma_f32_16x16x32_bf16(a1, b3, c13, 0, 0, 0);
        a0 = a0n; a1 = a1n; b0 = b0n; b1 = b1n; b2 = b2n; b3 = b3n;
    }

    const int row0 = bm + w * 16 + kg * 4;
    const int colb = bn + rc;
#define EPI(ACC, HOFF, CT) {                                                  \
        const int col = colb + (CT) * 16;                                     \
        const float bb = bias ? bias[col] : 0.0f;                             \
        _Pragma("unroll")                                                     \
        for (int i = 0; i < 4; ++i) {                                         \
            const float v = (ACC)[i] + bb;                                    \
            const size_t off = (size_t)(row0 + (HOFF) + i) * ldc + col;       \
            if (Cf) Cf[off] = v;                                              \
            if (Cb) Cb[off] = __float2bfloat16(v);                            \
        }}
    EPI(c00, 0, 0)  EPI(c01, 0, 1)  EPI(c02, 0, 2)  EPI(c03, 0, 3)
    EPI(c10, 64, 0) EPI(c11, 64, 1) EPI(c12, 64, 2) EPI(c13, 64, 3)
#undef EPI
}

// ---------------------------------------------------------------------------
// trans: [0,256) W1t = bf16(W1^T) via 64x64 LDS tiles (coalesced both sides);
//        block 256: gxbias = bih + bhh
// ---------------------------------------------------------------------------
__global__ __launch_bounds__(256) void trans_kernel(
    const float* __restrict__ W1, const float* __restrict__ bih,
    const float* __restrict__ bhh,
    __hip_bfloat16* __restrict__ W1t, float* __restrict__ gxbias)
{
    const int bid = blockIdx.x, t = threadIdx.x;
    if (bid < 256) {
        __shared__ float lds[64][65];
        const int br = bid >> 3, bc = bid & 7;      // W1 row block (k), col block (j)
        const int r0 = t >> 4, c4 = (t & 15) * 4;
        #pragma unroll
        for (int u = 0; u < 4; ++u) {
            const int row = r0 + u * 16;
            const float4 v = *reinterpret_cast<const float4*>(
                &W1[(size_t)(br * 64 + row) * 512 + bc * 64 + c4]);
            lds[row][c4 + 0] = v.x; lds[row][c4 + 1] = v.y;
            lds[row][c4 + 2] = v.z; lds[row][c4 + 3] = v.w;
        }
        __syncthreads();
        const int jj0 = t >> 4, kk4 = (t & 15) * 4;
        #pragma unroll
        for (int u = 0; u < 4; ++u) {
            const int jj = jj0 + u * 16;
            __hip_bfloat16 o[4] = {
                __float2bfloat16(lds[kk4 + 0][jj]), __float2bfloat16(lds[kk4 + 1][jj]),
                __float2bfloat16(lds[kk4 + 2][jj]), __float2bfloat16(lds[kk4 + 3][jj])};
            *reinterpret_cast<ushort4*>(
                &W1t[(size_t)(bc * 64 + jj) * 2048 + br * 64 + kk4]) =
                *reinterpret_cast<const ushort4*>(o);
        }
    } else {
        gxbias[t] = bih[t] + bhh[t];
    }
}

// ---------------------------------------------------------------------------
// prep: [0,32) Weffb tiles (128x64, K=2048, A=W2 f32, B=W1t bf16);
//       [32,40) beff f32; [40,168) Gx = x@Wih^T + gxbias (f32 A/B, swizzled)
// ---------------------------------------------------------------------------
__global__ __launch_bounds__(256) void prep_kernel(
    const float* __restrict__ x, const float* __restrict__ W1t_dummy,
    const float* __restrict__ W2, const float* __restrict__ b1,
    const float* __restrict__ b2, const float* __restrict__ Wih,
    const __hip_bfloat16* __restrict__ W1t, const float* __restrict__ gxbias,
    __hip_bfloat16* __restrict__ Weffb, float* __restrict__ beff,
    float* __restrict__ Gx)
{
    const int bid = blockIdx.x;
    if (bid < 32) {
        const int bm = (bid >> 3) * 128, bn = (bid & 7) * 64;
        mfma_tile128<float, __hip_bfloat16>(W2, 2048, W1t, 2048, 2048, bm, bn,
                                            nullptr, nullptr, 512, Weffb);
    } else if (bid < 40) {
        const int w = threadIdx.x >> 6, j = threadIdx.x & 63;
        const int base = (bid - 32) * 64 + w * 16;
        for (int o = 0; o < 16; ++o) {
            const int i = base + o;
            float s = 0.0f;
            #pragma unroll
            for (int m = 0; m < 32; ++m)
                s = fmaf(W2[(size_t)i * 2048 + j + 64 * m], b1[j + 64 * m], s);
            s = dpp_sum64_lane63(s);
            if (j == 63) beff[i] = s + b2[i];
        }
    } else {
        const int b = bid - 40;                       // 128 tiles, 40%8==0
        const int tile = (b & 7) * 16 + (b >> 3);     // XCD-contiguous panels
        const int bm = (tile >> 2) * 128, bn = (tile & 3) * 64;
        mfma_tile128<float, float>(x, 512, Wih, 512, 512, bm, bn, gxbias,
                                   Gx, 256, nullptr);
    }
}

// ---------------------------------------------------------------------------
// fused: [0,16) fixed-point phase (64 chunk-waves);
//        [16,16+fore_cnt) fore tiles (XCD-swizzled); remaining = Gf tiles.
// ---------------------------------------------------------------------------
__global__ __launch_bounds__(256) void fused_kernel(
    int phase, int first, int last,
    int fore_cnt, int gf_cnt,
    const float* __restrict__ x, const __hip_bfloat16* __restrict__ Weffb,
    const float* __restrict__ Wih, const float* __restrict__ fore_in,
    const float* __restrict__ beff, const float* __restrict__ Gx,
    const float* __restrict__ Whh, const float* __restrict__ Whr,
    const float* __restrict__ hprev, float* __restrict__ hnext,
    float* __restrict__ P, float* __restrict__ Q,
    float* __restrict__ c_hist, float* __restrict__ p,
    float* __restrict__ fore, float* __restrict__ Gf)
{
    if (blockIdx.x < 16) {
        const int chunk = blockIdx.x * 4 + (threadIdx.x >> 6);  // 0..63
        const int j = threadIdx.x & 63;
        const float wi = Whh[j], wf = Whh[64 + j];
        const float wg2 = Whh[128 + j], wo = Whh[192 + j];
        const float* ab = Gx + (size_t)chunk * 64 * 256 + j;

        float hp = 0.0f;
        if (!first) {
            const int idx = chunk * 64 - 1 + j;
            hp = (idx >= 0) ? hprev[idx] : 0.0f;
        }

        if (phase == 0) {
            float Pv = 1.0f, Qv = 0.0f;
            #pragma unroll 8
            for (int s = 0; s < 64; ++s) {
                const float hs = first ? 0.0f : readlane_s(hp, s);
                const float ai = ab[s * 256]       + wi  * hs;
                const float af = ab[s * 256 + 64]  + wf  * hs;
                const float ag = ab[s * 256 + 128] + wg2 * hs;
                const float si = sig_f(ai);
                const float sf = sig_f(af);
                const float tg = tanh_f(ag);
                Pv = sf * Pv;
                Qv = fmaf(sf, Qv, si * tg);
            }
            P[chunk * 64 + j] = Pv;
            Q[chunk * 64 + j] = Qv;
        } else {
            const float whr = Whr[j];
            float c = 0.0f;
            #pragma unroll 8
            for (int m = 0; m < chunk; ++m)
                c = fmaf(P[m * 64 + j], c, Q[m * 64 + j]);
            float vp = 0.0f;
            #pragma unroll 4
            for (int s = 0; s < 64; ++s) {
                const float hs = first ? 0.0f : readlane_s(hp, s);
                const float ai = ab[s * 256]       + wi  * hs;
                const float af = ab[s * 256 + 64]  + wf  * hs;
                const float ag = ab[s * 256 + 128] + wg2 * hs;
                const float ao = ab[s * 256 + 192] + wo  * hs;
                const float si = sig_f(ai);
                const float sf = sig_f(af);
                const float tg = tanh_f(ag);
                const float so = sig_f(ao);
                c = fmaf(sf, c, si * tg);
                if (last) c_hist[(size_t)(chunk * 64 + s) * 64 + j] = c;
                const float tc = tanh_f(c);
                float hv = tc * (so * whr);
                hv = dpp_sum64_lane63(hv);
                const float hn = readlane63(hv);
                vp = (j == s) ? hn : vp;
            }
            hnext[chunk * 64 + j] = vp;
            if (last) p[chunk * 64 + j] = vp;
        }
        return;
    }

    const int bt = blockIdx.x - 16;
    if (bt < fore_cnt) {                   // fore: 1024 tiles (128 panels x 8)
        const int tile = (bt & 7) * 128 + (bt >> 3);   // XCD-contiguous panels
        const int bm = (tile >> 3) * 128, bn = (tile & 7) * 64;
        mfma_tile128<float, __hip_bfloat16>(x, 512, Weffb, 512, 512, bm, bn,
                                            beff, fore, 512, nullptr);
    } else if (bt < fore_cnt + gf_cnt) {   // Gf: 128 tiles (32 panels x 4)
        const int g = bt - fore_cnt;
        const int tile = (g & 7) * 16 + (g >> 3);
        const int bm = (tile >> 2) * 128, bn = (tile & 3) * 64;
        mfma_tile128<float, float>(fore_in, 512, Wih, 512, 512, bm, bn,
                                   nullptr, Gf, 256, nullptr);
    }
}

// ---------------------------------------------------------------------------
// finish: [0,64) forecast cells (exact); [64,128) progress broadcast
// ---------------------------------------------------------------------------
__global__ __launch_bounds__(256) void finish_kernel(
    const float* __restrict__ Gf,
    const float* __restrict__ Whh, const float* __restrict__ bih,
    const float* __restrict__ bhh, const float* __restrict__ Whr,
    const float* __restrict__ c_hist, const float* __restrict__ p,
    float* __restrict__ out)
{
    constexpr int S = 4096, BS = 4 * 4096;
    const int bid = blockIdx.x;
    if (bid < 64) {
        const int w = threadIdx.x >> 6, j = threadIdx.x & 63;
        const float bi0 = bih[j]       + bhh[j];
        const float bi1 = bih[64 + j]  + bhh[64 + j];
        const float bi2 = bih[128 + j] + bhh[128 + j];
        const float bi3 = bih[192 + j] + bhh[192 + j];
        for (int o = 0; o < 16; ++o) {
            const int t = bid * 64 + w * 16 + o;
            const float h2 = p[t];
            const float c2 = c_hist[(size_t)t * 64 + j];
            const float* G = Gf + (size_t)t * 256;
            const float gi = G[j]       + bi0 + Whh[j] * h2;
            const float gf = G[64 + j]  + bi1 + Whh[64 + j] * h2;
            const float gg = G[128 + j] + bi2 + Whh[128 + j] * h2;
            const float go = G[192 + j] + bi3 + Whh[192 + j] * h2;
            const float cf = fsig(gf) * c2 + fsig(gi) * ftanh(gg);
            float hv = fsig(go) * ftanh(cf) * Whr[j];
            hv = dpp_sum64_lane63(hv);
            if (j == 63) {
                out[BS + 0 * S + t] = hv;
                out[BS + 1 * S + t] = hv;
                out[BS + 2 * S + t] = hv;
                out[BS + 3 * S + t] = hv;
            }
        }
    } else {
        const int i = (bid - 64) * 256 + threadIdx.x;
        out[i] = p[i & (S - 1)];
    }
}

extern "C" void kernel_launch(void* const* d_in, const int* in_sizes, int n_in,
                              void* d_out, int out_size, void* d_ws, size_t ws_size,
                              hipStream_t stream) {
    const float* x   = (const float*)d_in[0];
    const float* W1  = (const float*)d_in[1];
    const float* b1  = (const float*)d_in[2];
    const float* W2  = (const float*)d_in[3];
    const float* b2  = (const float*)d_in[4];
    const float* Wih = (const float*)d_in[5];
    const float* Whh = (const float*)d_in[6];
    const float* bih = (const float*)d_in[7];
    const float* bhh = (const float*)d_in[8];
    const float* Whr = (const float*)d_in[9];
    float* out = (float*)d_out;

    constexpr int Bb = 4, S = 4096;
    const int M = Bb * S; // 16384

    // workspace layout
    float* ws      = (float*)d_ws;
    float* beff    = ws;                         // 512
    float* gxbias  = beff + 512;                 // 256
    float* Gx      = gxbias + 256;               // 4096*256
    float* Gf      = Gx + S * 256;               // 4096*256
    float* c_hist  = Gf + S * 256;               // 4096*64
    float* p       = c_hist + S * 64;            // 4096
    float* Pp      = p + S;                      // 4096
    float* Qq      = Pp + S;                     // 4096
    float* h0      = Qq + S;                     // 4096
    float* h1      = h0 + S;                     // 4096
    __hip_bfloat16* W1t   = (__hip_bfloat16*)(h1 + S);   // 512*2048 (transposed)
    __hip_bfloat16* Weffb = W1t + 512 * 2048;            // 512*512

    float* fore = out + 2 * M;                   // (16384,512) region of d_out

    // 1) W1 transpose + gxbias
    trans_kernel<<<257, 256, 0, stream>>>(W1, bih, bhh, W1t, gxbias);

    // 2) Weffb (MFMA) + beff + Gx (MFMA)
    prep_kernel<<<168, 256, 0, stream>>>(
        x, nullptr, W2, b1, b2, Wih, W1t, gxbias, Weffb, beff, Gx);

    // 3) fixed-point (K=2). K1 carries ALL 1024 fore tiles; K2 the 128 Gf
    //    tiles; K3/K4 scan-only.
    fused_kernel<<<16 + 1024, 256, 0, stream>>>(
        0, 1, 0, 1024, 0, x, Weffb, Wih, fore, beff, Gx, Whh, Whr,
        h0, h0, Pp, Qq, c_hist, p, fore, Gf);
    fused_kernel<<<16 + 128, 256, 0, stream>>>(
        1, 1, 0, 0, 128, x, Weffb, Wih, fore, beff, Gx, Whh, Whr,
        h0, h0, Pp, Qq, c_hist, p, fore, Gf);
    fused_kernel<<<16, 256, 0, stream>>>(
        0, 0, 0, 0, 0, x, Weffb, Wih, fore, beff, Gx, Whh, Whr,
        h0, h1, Pp, Qq, c_hist, p, fore, Gf);
    fused_kernel<<<16, 256, 0, stream>>>(
        1, 0, 1, 0, 0, x, Weffb, Wih, fore, beff, Gx, Whh, Whr,
        h0, h1, Pp, Qq, c_hist, p, fore, Gf);

    // 4) forecast cells + output broadcasts
    finish_kernel<<<128, 256, 0, stream>>>(
        Gf, Whh, bih, bhh, Whr, c_hist, p, out);
}